// Round 10
// baseline (1121.883 us; speedup 1.0000x reference)
//
#include <hip/hip_runtime.h>
#include <math.h>

typedef _Float16 f16;
typedef _Float16 f16x2 __attribute__((ext_vector_type(2)));
typedef _Float16 f16x8 __attribute__((ext_vector_type(8)));
typedef float f32x4 __attribute__((ext_vector_type(4)));
typedef unsigned long long u64;

#define LDIM 128
#define HOUT 256

// LDS layout (bytes): h-panels 2 x 18432 @ 0, 18432; x-panels 2 x 9216 @ 36864, 46080.
// h-panel: [plane 2][row 18][c 256] f16, row 512 B, plane 9216 B, 16B-granule XOR swizzle.
// x-panel: [plane 2][row 18][c 128] f16, row 256 B, plane 4608 B, same swizzle.
#define XB0 36864

__device__ __forceinline__ float tanh_fast(float x) {
    float a = fabsf(x);
    float e = __expf(-2.0f * a);
    float r = (1.0f - e) / (1.0f + e);
    return copysignf(r, x);
}

__device__ __forceinline__ void st_mb(u64* p, u64 v) {
    __hip_atomic_store(p, v, __ATOMIC_RELAXED, __HIP_MEMORY_SCOPE_AGENT);
}
__device__ __forceinline__ u64 ld_mb(const u64* p) {
    return __hip_atomic_load(p, __ATOMIC_RELAXED, __HIP_MEMORY_SCOPE_AGENT);
}

// A-frag packings (f16):
//  wt_i: [(((s*4+kk)*16+h16)*64+lane)*8+j] = W_i[h16*16+(lane&15)][kk*32+(lane>>4)*8+j][s]
//  wt_h: [(((s*8+kk)*16+h16)*64+lane)*8+j] = W_h[h16*16+(lane&15)][kk*32+(lane>>4)*8+j][s]
__global__ void prep_w(const float* __restrict__ wi, f16* __restrict__ wtif,
                       const float* __restrict__ wh, f16* __restrict__ wthf)
{
    int idx = blockIdx.x * 256 + threadIdx.x;
    const int ni = 3 * 4 * 16 * 64 * 8;      // 98304
    if (idx < ni) {
        int j    = idx & 7;
        int lane = (idx >> 3) & 63;
        int h16  = (idx >> 9) & 15;
        int kk   = (idx >> 13) & 3;
        int s    = idx >> 15;
        int h = h16 * 16 + (lane & 15);
        int c = kk * 32 + (lane >> 4) * 8 + j;
        wtif[idx] = (f16)wi[(h * 128 + c) * 3 + s];
    } else {
        int e = idx - ni;
        if (e >= 3 * 8 * 16 * 64 * 8) return;  // 196608
        int j    = e & 7;
        int lane = (e >> 3) & 63;
        int h16  = (e >> 9) & 15;
        int kk   = (e >> 13) & 7;
        int s    = e >> 16;
        int h = h16 * 16 + (lane & 15);
        int c = kk * 32 + (lane >> 4) * 8 + j;
        wthf[e] = (f16)wh[(h * 256 + c) * 3 + s];
    }
}

// stage x[b][t2][128c][l0-1 .. l0+16] -> x-panel (hi/lo split, swizzled); normal loads
__device__ __forceinline__ void stage_x(char* xp, const float* __restrict__ xt,
                                        int l0, int tid)
{
    const int c = tid >> 2, q = tid & 3;
    f32x4 v = *(const f32x4*)(xt + c * LDIM + l0 + q * 4);
#pragma unroll
    for (int i = 0; i < 4; ++i) {
        int r = q * 4 + i + 1;
        float xx = v[i];
        f16 h = (f16)xx, lo = (f16)(xx - (float)h);
        int off = r * 256 + ((((c >> 3) ^ (r & 7)) << 4)) + (c & 7) * 2;
        *(f16*)(xp + off) = h;
        *(f16*)(xp + 4608 + off) = lo;
    }
    if (tid < 256) {
        int e = tid >> 7, cc = tid & 127;
        int l = e ? l0 + 16 : l0 - 1;
        int r = e ? 17 : 0;
        float xx = ((unsigned)l < 128u) ? xt[cc * LDIM + l] : 0.f;
        f16 h = (f16)xx, lo = (f16)(xx - (float)h);
        int off = r * 256 + ((((cc >> 3) ^ (r & 7)) << 4)) + (cc & 7) * 2;
        *(f16*)(xp + off) = h;
        *(f16*)(xp + 4608 + off) = lo;
    }
}

// Z-conv: zn += conv_i over 128 c from x-panel; A-frags streamed from L2
__device__ __forceinline__ void zconv(const char* xp, const f16* __restrict__ wti,
                                      int wid, int lane, int l16, int g, f32x4 zn[2])
{
#pragma unroll
    for (int kk = 0; kk < 4; ++kk) {
        f16x8 ai[3][2];
#pragma unroll
        for (int s = 0; s < 3; ++s)
#pragma unroll
            for (int hf = 0; hf < 2; ++hf)
                ai[s][hf] = *(const f16x8*)(wti +
                    ((((s * 4 + kk) * 16 + wid * 2 + hf) * 64 + lane) << 3));
#pragma unroll
        for (int s = 0; s < 3; ++s) {
            int r = l16 + s;
            int base = r * 256 + ((((kk * 4 + g) ^ (r & 7)) << 4));
            f16x8 b0 = *(const f16x8*)(xp + base);
            f16x8 b1 = *(const f16x8*)(xp + 4608 + base);
#pragma unroll
            for (int hf = 0; hf < 2; ++hf) {
                zn[hf] = __builtin_amdgcn_mfma_f32_16x16x32_f16(ai[s][hf], b0, zn[hf], 0, 0, 0);
                zn[hf] = __builtin_amdgcn_mfma_f32_16x16x32_f16(ai[s][hf], b1, zn[hf], 0, 0, 0);
            }
        }
    }
}

// h-conv, single shift s, from h-panel (weights from resident registers)
__device__ __forceinline__ void hconv_s(const char* hp, const f16x8 (*afr)[2],
                                        int l16, int g, int s, f32x4 hacc[2])
{
#pragma unroll
    for (int kk = 0; kk < 8; ++kk) {
        int r = l16 + s;
        int base = r * 512 + ((((kk * 4 + g) ^ (r & 7)) << 4));
        f16x8 b0 = *(const f16x8*)(hp + base);
        f16x8 b1 = *(const f16x8*)(hp + 9216 + base);
#pragma unroll
        for (int hf = 0; hf < 2; ++hf) {
            hacc[hf] = __builtin_amdgcn_mfma_f32_16x16x32_f16(afr[kk][hf], b0, hacc[hf], 0, 0, 0);
            hacc[hf] = __builtin_amdgcn_mfma_f32_16x16x32_f16(afr[kk][hf], b1, hacc[hf], 0, 0, 0);
        }
    }
}

// ---------------- Fused persistent kernel ----------------
// 128 blocks = 16 b x 8 l-windows; 512 thr = 8 waves, wave owns 32 h (h16 = wid*2+hf).
// Cross-block handoff: self-timestamped halo mailbox (u64 {tag, f32 bits}, relaxed sc1
// atomics; tag+value atomic together; double-buffered by t&1; skew <= 1 step).
// amdgpu_waves_per_eu(2,2): max 2 waves/SIMD -> 256-VGPR budget so the 192-VGPR
// wt_h A-frag set stays resident (R9 spilled at the default 128 cap -> 300 MB scratch).
__global__ void __launch_bounds__(512)
__attribute__((amdgpu_waves_per_eu(2, 2)))
rnn_fused(const float* __restrict__ x, const f16* __restrict__ wti,
          const f16* __restrict__ wth, float* __restrict__ out,
          u64* __restrict__ mbox)
{
    __shared__ __align__(16) char smem[55296];
    const int tid  = threadIdx.x;
    const int lane = tid & 63, wid = tid >> 6;   // 8 waves
    const int b    = blockIdx.x & 15;
    const int lw   = blockIdx.x >> 4;            // 0..7
    const int l0   = lw * 16;
    const int l16  = lane & 15, g = lane >> 4;
    const long HL  = (long)HOUT * LDIM;
    float* outb    = out + (long)b * (64 * HL);
    const float* xb = x + (long)b * (64L * 128 * LDIM);

    // publish duty for this thread's column (l0 + l16)
    int edge = -1;
    if (l16 == 0  && lw > 0) edge = 0;   // left edge -> consumed by lw-1
    if (l16 == 15 && lw < 7) edge = 1;   // right edge -> consumed by lw+1
    u64* mb_pub = (edge >= 0) ? (mbox + (((b * 8 + lw) * 2 + edge) * 2) * 256) : nullptr;

    // ---- wt_h A-frags resident in registers (192 VGPR)
    f16x8 afrh[3][8][2];
#pragma unroll
    for (int s = 0; s < 3; ++s)
#pragma unroll
        for (int kk = 0; kk < 8; ++kk)
#pragma unroll
            for (int hf = 0; hf < 2; ++hf)
                afrh[s][kk][hf] = *(const f16x8*)(wth +
                    ((((s * 8 + kk) * 16 + wid * 2 + hf) * 64 + lane) << 3));

    // ---- prologue: stage x[0], x[1]; Z_0 into zcur
    stage_x(smem + XB0, xb, l0, tid);
    stage_x(smem + XB0 + 9216, xb + 128 * LDIM, l0, tid);
    __syncthreads();
    f32x4 zcur[2] = {};
    zconv(smem + XB0, wti, wid, lane, l16, g, zcur);
    __syncthreads();   // protect x-panel 0 rewrite at t=0

    for (int t = 0; t < 64; ++t) {
        float* outt = outb + (long)t * HL;

        // ---- stage x[t+2] (independent of recurrence)
        if (t + 2 < 64)
            stage_x(smem + XB0 + (t & 1) * 9216, xb + (long)(t + 2) * (128 * LDIM), l0, tid);

        // ---- Z_{t+1} from the x-panel staged at t-1
        f32x4 zn[2] = {};
        if (t < 63)
            zconv(smem + XB0 + ((t + 1) & 1) * 9216, wti, wid, lane, l16, g, zn);

        // ---- h-conv s=1 (rows 1..16 only: own columns, no halo)
        f32x4 hacc[2] = {};
        char* hp = smem + ((t ^ 1) & 1) * 18432;   // panel holding h_{t-1}
        if (t > 0)
            hconv_s(hp, afrh[1], l16, g, 1, hacc);

        // ---- halo: poll self-timestamped mailbox (tag >= t), write rows 0/17
        if (t > 0) {
            const int par = (t ^ 1) & 1;           // slot parity of h_{t-1}
            if (tid < 256) {
                int c = tid;
                float xx = 0.f;
                if (lw > 0) {
                    const u64* p = mbox + ((((b * 8 + lw - 1) * 2 + 1) * 2 + par) * 256) + c;
                    u64 v = ld_mb(p);
                    while ((unsigned)(v >> 32) < (unsigned)t) {
                        __builtin_amdgcn_s_sleep(1);
                        v = ld_mb(p);
                    }
                    xx = __uint_as_float((unsigned)v);
                }
                f16 h = (f16)xx, lo = (f16)(xx - (float)h);
                int off = ((c >> 3) << 4) + (c & 7) * 2;                     // r=0
                *(f16*)(hp + off) = h;
                *(f16*)(hp + 9216 + off) = lo;
            } else {
                int c = tid - 256;
                float xx = 0.f;
                if (lw < 7) {
                    const u64* p = mbox + ((((b * 8 + lw + 1) * 2 + 0) * 2 + par) * 256) + c;
                    u64 v = ld_mb(p);
                    while ((unsigned)(v >> 32) < (unsigned)t) {
                        __builtin_amdgcn_s_sleep(1);
                        v = ld_mb(p);
                    }
                    xx = __uint_as_float((unsigned)v);
                }
                f16 h = (f16)xx, lo = (f16)(xx - (float)h);
                int off = 17 * 512 + ((((c >> 3) ^ 1) << 4)) + (c & 7) * 2;  // r=17
                *(f16*)(hp + off) = h;
                *(f16*)(hp + 9216 + off) = lo;
            }
        }
        __syncthreads();   // halo rows visible to all waves

        // ---- h-conv s=0,2 (use halo rows)
        if (t > 0) {
            hconv_s(hp, afrh[0], l16, g, 0, hacc);
            hconv_s(hp, afrh[2], l16, g, 2, hacc);
        }

        // ---- epilogue: h_t = tanh(hconv + Z_t); plain out stores, mailbox publish, panel write
        char* pw = smem + (t & 1) * 18432;
        u64* pub = (edge >= 0) ? (mb_pub + (t & 1) * 256) : nullptr;
        const u64 tagw = ((u64)(unsigned)(t + 1)) << 32;
        const int r  = l16 + 1;
        const int rx = r & 7;
#pragma unroll
        for (int hf = 0; hf < 2; ++hf) {
            float hv[4];
#pragma unroll
            for (int vv = 0; vv < 4; ++vv) {
                int c = wid * 32 + hf * 16 + g * 4 + vv;
                hv[vv] = tanh_fast(hacc[hf][vv] + zcur[hf][vv]);
                outt[(long)c * LDIM + l0 + l16] = hv[vv];   // plain store: no reader in-kernel
                if (edge >= 0)
                    st_mb(&pub[c], tagw | (u64)__float_as_uint(hv[vv]));
            }
#pragma unroll
            for (int p = 0; p < 2; ++p) {
                int c = wid * 32 + hf * 16 + g * 4 + p * 2;
                float a0 = hv[2 * p], a1 = hv[2 * p + 1];
                f16 h0 = (f16)a0, h1 = (f16)a1;
                f16 e0 = (f16)(a0 - (float)h0), e1 = (f16)(a1 - (float)h1);
                int off = r * 512 + ((((c >> 3) ^ rx) << 4)) + (c & 7) * 2;
                f16x2 hw; hw[0] = h0; hw[1] = h1;
                f16x2 ew; ew[0] = e0; ew[1] = e1;
                *(f16x2*)(pw + off) = hw;
                *(f16x2*)(pw + 9216 + off) = ew;
            }
        }
        zcur[0] = zn[0];
        zcur[1] = zn[1];

        __syncthreads();   // protect h-panel(t&1) and x-panel reuse next step
    }
}

extern "C" void kernel_launch(void* const* d_in, const int* in_sizes, int n_in,
                              void* d_out, int out_size, void* d_ws, size_t ws_size,
                              hipStream_t stream)
{
    const float* x   = (const float*)d_in[0];   // [16][64][128][128]
    const float* W_i = (const float*)d_in[1];   // [256][128][3]
    const float* W_h = (const float*)d_in[2];   // [256][256][3]
    float* out = (float*)d_out;                 // [16][64][256][128]

    f16* wt_i = (f16*)d_ws;                              // 196608 B
    f16* wt_h = (f16*)((char*)d_ws + 196608);            // 393216 B
    u64* mbox = (u64*)((char*)d_ws + 589824);            // 16*8*2*2*256*8 = 131072 B

    prep_w<<<1152, 256, 0, stream>>>(W_i, wt_i, W_h, wt_h);
    hipMemsetAsync(mbox, 0, 131072, stream);             // tags <- 0 (< any awaited t)

    rnn_fused<<<128, 512, 0, stream>>>(x, wt_i, wt_h, out, mbox);
}

// Round 11
// 470.964 us; speedup vs baseline: 2.3821x; 2.3821x over previous
//
#include <hip/hip_runtime.h>
#include <math.h>

typedef _Float16 f16;
typedef _Float16 f16x2 __attribute__((ext_vector_type(2)));
typedef _Float16 f16x8 __attribute__((ext_vector_type(8)));
typedef float f32x4 __attribute__((ext_vector_type(4)));
typedef unsigned long long u64;

#define LDIM 128
#define HOUT 256

// LDS layout (bytes): h-panels 2 x 18432 @ 0, 18432; x-panels 2 x 9216 @ 36864, 46080.
// h-panel: [plane 2][row 18][c 256] f16, row 512 B, plane 9216 B, 16B-granule XOR swizzle.
// x-panel: [plane 2][row 18][c 128] f16, row 256 B, plane 4608 B, same swizzle.
#define XB0 36864

__device__ __forceinline__ float tanh_fast(float x) {
    float a = fabsf(x);
    float e = __expf(-2.0f * a);
    float r = (1.0f - e) / (1.0f + e);
    return copysignf(r, x);
}

__device__ __forceinline__ void st_mb(u64* p, u64 v) {
    __hip_atomic_store(p, v, __ATOMIC_RELAXED, __HIP_MEMORY_SCOPE_AGENT);
}
__device__ __forceinline__ u64 ld_mb(const u64* p) {
    return __hip_atomic_load(p, __ATOMIC_RELAXED, __HIP_MEMORY_SCOPE_AGENT);
}

// A-frag packings (f16):
//  wt_i: [(((s*4+kk)*16+h16)*64+lane)*8+j] = W_i[h16*16+(lane&15)][kk*32+(lane>>4)*8+j][s]
//  wt_h: [(((s*8+kk)*16+h16)*64+lane)*8+j] = W_h[h16*16+(lane&15)][kk*32+(lane>>4)*8+j][s]
__global__ void prep_w(const float* __restrict__ wi, f16* __restrict__ wtif,
                       const float* __restrict__ wh, f16* __restrict__ wthf)
{
    int idx = blockIdx.x * 256 + threadIdx.x;
    const int ni = 3 * 4 * 16 * 64 * 8;      // 98304
    if (idx < ni) {
        int j    = idx & 7;
        int lane = (idx >> 3) & 63;
        int h16  = (idx >> 9) & 15;
        int kk   = (idx >> 13) & 3;
        int s    = idx >> 15;
        int h = h16 * 16 + (lane & 15);
        int c = kk * 32 + (lane >> 4) * 8 + j;
        wtif[idx] = (f16)wi[(h * 128 + c) * 3 + s];
    } else {
        int e = idx - ni;
        if (e >= 3 * 8 * 16 * 64 * 8) return;  // 196608
        int j    = e & 7;
        int lane = (e >> 3) & 63;
        int h16  = (e >> 9) & 15;
        int kk   = (e >> 13) & 7;
        int s    = e >> 16;
        int h = h16 * 16 + (lane & 15);
        int c = kk * 32 + (lane >> 4) * 8 + j;
        wthf[e] = (f16)wh[(h * 256 + c) * 3 + s];
    }
}

// stage x[b][t2][128c][l0-1 .. l0+16] -> x-panel (hi/lo split, swizzled); normal loads
__device__ __forceinline__ void stage_x(char* xp, const float* __restrict__ xt,
                                        int l0, int tid)
{
    const int c = tid >> 2, q = tid & 3;
    f32x4 v = *(const f32x4*)(xt + c * LDIM + l0 + q * 4);
#pragma unroll
    for (int i = 0; i < 4; ++i) {
        int r = q * 4 + i + 1;
        float xx = v[i];
        f16 h = (f16)xx, lo = (f16)(xx - (float)h);
        int off = r * 256 + ((((c >> 3) ^ (r & 7)) << 4)) + (c & 7) * 2;
        *(f16*)(xp + off) = h;
        *(f16*)(xp + 4608 + off) = lo;
    }
    if (tid < 256) {
        int e = tid >> 7, cc = tid & 127;
        int l = e ? l0 + 16 : l0 - 1;
        int r = e ? 17 : 0;
        float xx = ((unsigned)l < 128u) ? xt[cc * LDIM + l] : 0.f;
        f16 h = (f16)xx, lo = (f16)(xx - (float)h);
        int off = r * 256 + ((((cc >> 3) ^ (r & 7)) << 4)) + (cc & 7) * 2;
        *(f16*)(xp + off) = h;
        *(f16*)(xp + 4608 + off) = lo;
    }
}

// Z-conv: zn += conv_i over 128 c from x-panel; A-frags streamed from L2
__device__ __forceinline__ void zconv(const char* xp, const f16* __restrict__ wti,
                                      int wid, int lane, int l16, int g, f32x4 zn[2])
{
#pragma unroll
    for (int kk = 0; kk < 4; ++kk) {
#pragma unroll
        for (int s = 0; s < 3; ++s) {
            f16x8 a0 = *(const f16x8*)(wti +
                ((((s * 4 + kk) * 16 + wid * 2 + 0) * 64 + lane) << 3));
            f16x8 a1 = *(const f16x8*)(wti +
                ((((s * 4 + kk) * 16 + wid * 2 + 1) * 64 + lane) << 3));
            int r = l16 + s;
            int base = r * 256 + ((((kk * 4 + g) ^ (r & 7)) << 4));
            f16x8 b0 = *(const f16x8*)(xp + base);
            f16x8 b1 = *(const f16x8*)(xp + 4608 + base);
            zn[0] = __builtin_amdgcn_mfma_f32_16x16x32_f16(a0, b0, zn[0], 0, 0, 0);
            zn[0] = __builtin_amdgcn_mfma_f32_16x16x32_f16(a0, b1, zn[0], 0, 0, 0);
            zn[1] = __builtin_amdgcn_mfma_f32_16x16x32_f16(a1, b0, zn[1], 0, 0, 0);
            zn[1] = __builtin_amdgcn_mfma_f32_16x16x32_f16(a1, b1, zn[1], 0, 0, 0);
        }
    }
}

// h-conv, single shift s: A-frags streamed from L2 (wt_h, 384 KB, L2-resident),
// B-frags from h-panel. No register-resident weight state -> no spills.
__device__ __forceinline__ void hconv_s(const char* hp, const f16* __restrict__ wth,
                                        int s, int wid, int lane, int l16, int g,
                                        f32x4 hacc[2])
{
#pragma unroll
    for (int kk = 0; kk < 8; ++kk) {
        f16x8 a0 = *(const f16x8*)(wth +
            ((((s * 8 + kk) * 16 + wid * 2 + 0) * 64 + lane) << 3));
        f16x8 a1 = *(const f16x8*)(wth +
            ((((s * 8 + kk) * 16 + wid * 2 + 1) * 64 + lane) << 3));
        int r = l16 + s;
        int base = r * 512 + ((((kk * 4 + g) ^ (r & 7)) << 4));
        f16x8 b0 = *(const f16x8*)(hp + base);
        f16x8 b1 = *(const f16x8*)(hp + 9216 + base);
        hacc[0] = __builtin_amdgcn_mfma_f32_16x16x32_f16(a0, b0, hacc[0], 0, 0, 0);
        hacc[0] = __builtin_amdgcn_mfma_f32_16x16x32_f16(a0, b1, hacc[0], 0, 0, 0);
        hacc[1] = __builtin_amdgcn_mfma_f32_16x16x32_f16(a1, b0, hacc[1], 0, 0, 0);
        hacc[1] = __builtin_amdgcn_mfma_f32_16x16x32_f16(a1, b1, hacc[1], 0, 0, 0);
    }
}

// ---------------- Fused persistent kernel ----------------
// 128 blocks = 16 b x 8 l-windows; 512 thr = 8 waves, wave owns 32 h (h16 = wid*2+hf).
// Cross-block handoff: self-timestamped halo mailbox (u64 {tag, f32 bits}, relaxed sc1
// atomics; tag+value atomic together; double-buffered by t&1; skew <= 1 step).
// Weights are NOT register-resident: both wt_i and wt_h A-frags stream from per-XCD L2
// on every use (R9/R10 proved the allocator spills a resident set to HBM scratch).
__global__ void __launch_bounds__(512)
rnn_fused(const float* __restrict__ x, const f16* __restrict__ wti,
          const f16* __restrict__ wth, float* __restrict__ out,
          u64* __restrict__ mbox)
{
    __shared__ __align__(16) char smem[55296];
    const int tid  = threadIdx.x;
    const int lane = tid & 63, wid = tid >> 6;   // 8 waves
    const int b    = blockIdx.x & 15;
    const int lw   = blockIdx.x >> 4;            // 0..7
    const int l0   = lw * 16;
    const int l16  = lane & 15, g = lane >> 4;
    const long HL  = (long)HOUT * LDIM;
    float* outb    = out + (long)b * (64 * HL);
    const float* xb = x + (long)b * (64L * 128 * LDIM);

    // publish duty for this thread's column (l0 + l16)
    int edge = -1;
    if (l16 == 0  && lw > 0) edge = 0;   // left edge -> consumed by lw-1
    if (l16 == 15 && lw < 7) edge = 1;   // right edge -> consumed by lw+1
    u64* mb_pub = (edge >= 0) ? (mbox + (((b * 8 + lw) * 2 + edge) * 2) * 256) : nullptr;

    // ---- prologue: stage x[0], x[1]; Z_0 into zcur
    stage_x(smem + XB0, xb, l0, tid);
    stage_x(smem + XB0 + 9216, xb + 128 * LDIM, l0, tid);
    __syncthreads();
    f32x4 zcur[2] = {};
    zconv(smem + XB0, wti, wid, lane, l16, g, zcur);
    __syncthreads();   // protect x-panel 0 rewrite at t=0

    for (int t = 0; t < 64; ++t) {
        float* outt = outb + (long)t * HL;

        // ---- stage x[t+2] (independent of recurrence)
        if (t + 2 < 64)
            stage_x(smem + XB0 + (t & 1) * 9216, xb + (long)(t + 2) * (128 * LDIM), l0, tid);

        // ---- Z_{t+1} from the x-panel staged at t-1
        f32x4 zn[2] = {};
        if (t < 63)
            zconv(smem + XB0 + ((t + 1) & 1) * 9216, wti, wid, lane, l16, g, zn);

        // ---- h-conv s=1 (rows 1..16 only: own columns, no halo)
        f32x4 hacc[2] = {};
        char* hp = smem + ((t ^ 1) & 1) * 18432;   // panel holding h_{t-1}
        if (t > 0)
            hconv_s(hp, wth, 1, wid, lane, l16, g, hacc);

        // ---- halo: poll self-timestamped mailbox (tag >= t), write rows 0/17
        if (t > 0) {
            const int par = (t ^ 1) & 1;           // slot parity of h_{t-1}
            if (tid < 256) {
                int c = tid;
                float xx = 0.f;
                if (lw > 0) {
                    const u64* p = mbox + ((((b * 8 + lw - 1) * 2 + 1) * 2 + par) * 256) + c;
                    u64 v = ld_mb(p);
                    while ((unsigned)(v >> 32) < (unsigned)t) {
                        __builtin_amdgcn_s_sleep(1);
                        v = ld_mb(p);
                    }
                    xx = __uint_as_float((unsigned)v);
                }
                f16 h = (f16)xx, lo = (f16)(xx - (float)h);
                int off = ((c >> 3) << 4) + (c & 7) * 2;                     // r=0
                *(f16*)(hp + off) = h;
                *(f16*)(hp + 9216 + off) = lo;
            } else {
                int c = tid - 256;
                float xx = 0.f;
                if (lw < 7) {
                    const u64* p = mbox + ((((b * 8 + lw + 1) * 2 + 0) * 2 + par) * 256) + c;
                    u64 v = ld_mb(p);
                    while ((unsigned)(v >> 32) < (unsigned)t) {
                        __builtin_amdgcn_s_sleep(1);
                        v = ld_mb(p);
                    }
                    xx = __uint_as_float((unsigned)v);
                }
                f16 h = (f16)xx, lo = (f16)(xx - (float)h);
                int off = 17 * 512 + ((((c >> 3) ^ 1) << 4)) + (c & 7) * 2;  // r=17
                *(f16*)(hp + off) = h;
                *(f16*)(hp + 9216 + off) = lo;
            }
        }
        __syncthreads();   // halo rows visible to all waves

        // ---- h-conv s=0,2 (use halo rows)
        if (t > 0) {
            hconv_s(hp, wth, 0, wid, lane, l16, g, hacc);
            hconv_s(hp, wth, 2, wid, lane, l16, g, hacc);
        }

        // ---- epilogue: h_t = tanh(hconv + Z_t); plain out stores, mailbox publish, panel write
        char* pw = smem + (t & 1) * 18432;
        u64* pub = (edge >= 0) ? (mb_pub + (t & 1) * 256) : nullptr;
        const u64 tagw = ((u64)(unsigned)(t + 1)) << 32;
        const int r  = l16 + 1;
        const int rx = r & 7;
#pragma unroll
        for (int hf = 0; hf < 2; ++hf) {
            float hv[4];
#pragma unroll
            for (int vv = 0; vv < 4; ++vv) {
                int c = wid * 32 + hf * 16 + g * 4 + vv;
                hv[vv] = tanh_fast(hacc[hf][vv] + zcur[hf][vv]);
                outt[(long)c * LDIM + l0 + l16] = hv[vv];   // plain store: no in-kernel reader
                if (edge >= 0)
                    st_mb(&pub[c], tagw | (u64)__float_as_uint(hv[vv]));
            }
#pragma unroll
            for (int p = 0; p < 2; ++p) {
                int c = wid * 32 + hf * 16 + g * 4 + p * 2;
                float a0 = hv[2 * p], a1 = hv[2 * p + 1];
                f16 h0 = (f16)a0, h1 = (f16)a1;
                f16 e0 = (f16)(a0 - (float)h0), e1 = (f16)(a1 - (float)h1);
                int off = r * 512 + ((((c >> 3) ^ rx) << 4)) + (c & 7) * 2;
                f16x2 hw; hw[0] = h0; hw[1] = h1;
                f16x2 ew; ew[0] = e0; ew[1] = e1;
                *(f16x2*)(pw + off) = hw;
                *(f16x2*)(pw + 9216 + off) = ew;
            }
        }
        zcur[0] = zn[0];
        zcur[1] = zn[1];

        __syncthreads();   // protect h-panel(t&1) and x-panel reuse next step
    }
}

extern "C" void kernel_launch(void* const* d_in, const int* in_sizes, int n_in,
                              void* d_out, int out_size, void* d_ws, size_t ws_size,
                              hipStream_t stream)
{
    const float* x   = (const float*)d_in[0];   // [16][64][128][128]
    const float* W_i = (const float*)d_in[1];   // [256][128][3]
    const float* W_h = (const float*)d_in[2];   // [256][256][3]
    float* out = (float*)d_out;                 // [16][64][256][128]

    f16* wt_i = (f16*)d_ws;                              // 196608 B
    f16* wt_h = (f16*)((char*)d_ws + 196608);            // 393216 B
    u64* mbox = (u64*)((char*)d_ws + 589824);            // 16*8*2*2*256*8 = 131072 B

    prep_w<<<1152, 256, 0, stream>>>(W_i, wt_i, W_h, wt_h);
    hipMemsetAsync(mbox, 0, 131072, stream);             // tags <- 0 (< any awaited t)

    rnn_fused<<<128, 512, 0, stream>>>(x, wt_i, wt_h, out, mbox);
}

// Round 12
// 418.746 us; speedup vs baseline: 2.6791x; 1.1247x over previous
//
#include <hip/hip_runtime.h>
#include <math.h>

typedef _Float16 f16;
typedef _Float16 f16x2 __attribute__((ext_vector_type(2)));
typedef _Float16 f16x8 __attribute__((ext_vector_type(8)));
typedef float f32x4 __attribute__((ext_vector_type(4)));
typedef unsigned long long u64;

#define LDIM 128
#define HOUT 256

// LDS layout (bytes):
//  h-panels 2 x 9216 @ 0, 9216          -- SINGLE-plane f16 [18 rows][256 c], row 512 B
//  x-panels 2 x 9216 @ 18432, 27648     -- [2 planes][18 rows][128 c], plane 4608 B
// All with 16B-granule XOR swizzle: granule ^= (row & 7).
#define XB0 18432

__device__ __forceinline__ float tanh_fast(float x) {
    float a = fabsf(x);
    float e = __expf(-2.0f * a);
    float r = (1.0f - e) / (1.0f + e);
    return copysignf(r, x);
}

__device__ __forceinline__ void st_mb(u64* p, u64 v) {
    __hip_atomic_store(p, v, __ATOMIC_RELAXED, __HIP_MEMORY_SCOPE_AGENT);
}
__device__ __forceinline__ u64 ld_mb(const u64* p) {
    return __hip_atomic_load(p, __ATOMIC_RELAXED, __HIP_MEMORY_SCOPE_AGENT);
}

// A-frag packings (f16):
//  wt_i: [(((s*4+kk)*16+h16)*64+lane)*8+j] = W_i[h16*16+(lane&15)][kk*32+(lane>>4)*8+j][s]
//  wt_h: [(((s*8+kk)*16+h16)*64+lane)*8+j] = W_h[h16*16+(lane&15)][kk*32+(lane>>4)*8+j][s]
__global__ void prep_w(const float* __restrict__ wi, f16* __restrict__ wtif,
                       const float* __restrict__ wh, f16* __restrict__ wthf)
{
    int idx = blockIdx.x * 256 + threadIdx.x;
    const int ni = 3 * 4 * 16 * 64 * 8;      // 98304
    if (idx < ni) {
        int j    = idx & 7;
        int lane = (idx >> 3) & 63;
        int h16  = (idx >> 9) & 15;
        int kk   = (idx >> 13) & 3;
        int s    = idx >> 15;
        int h = h16 * 16 + (lane & 15);
        int c = kk * 32 + (lane >> 4) * 8 + j;
        wtif[idx] = (f16)wi[(h * 128 + c) * 3 + s];
    } else {
        int e = idx - ni;
        if (e >= 3 * 8 * 16 * 64 * 8) return;  // 196608
        int j    = e & 7;
        int lane = (e >> 3) & 63;
        int h16  = (e >> 9) & 15;
        int kk   = (e >> 13) & 7;
        int s    = e >> 16;
        int h = h16 * 16 + (lane & 15);
        int c = kk * 32 + (lane >> 4) * 8 + j;
        wthf[e] = (f16)wh[(h * 256 + c) * 3 + s];
    }
}

// stage x[b][t2][128c][l0-1 .. l0+16] -> x-panel (hi/lo split, swizzled); normal loads
__device__ __forceinline__ void stage_x(char* xp, const float* __restrict__ xt,
                                        int l0, int tid)
{
    const int c = tid >> 2, q = tid & 3;
    f32x4 v = *(const f32x4*)(xt + c * LDIM + l0 + q * 4);
#pragma unroll
    for (int i = 0; i < 4; ++i) {
        int r = q * 4 + i + 1;
        float xx = v[i];
        f16 h = (f16)xx, lo = (f16)(xx - (float)h);
        int off = r * 256 + ((((c >> 3) ^ (r & 7)) << 4)) + (c & 7) * 2;
        *(f16*)(xp + off) = h;
        *(f16*)(xp + 4608 + off) = lo;
    }
    if (tid < 256) {
        int e = tid >> 7, cc = tid & 127;
        int l = e ? l0 + 16 : l0 - 1;
        int r = e ? 17 : 0;
        float xx = ((unsigned)l < 128u) ? xt[cc * LDIM + l] : 0.f;
        f16 h = (f16)xx, lo = (f16)(xx - (float)h);
        int off = r * 256 + ((((cc >> 3) ^ (r & 7)) << 4)) + (cc & 7) * 2;
        *(f16*)(xp + off) = h;
        *(f16*)(xp + 4608 + off) = lo;
    }
}

// Z-conv: zn += conv_i over 128 c from x-panel (hi+lo planes); A-frags streamed from L2
__device__ __forceinline__ void zconv(const char* xp, const f16* __restrict__ wti,
                                      int wid, int lane, int l16, int g, f32x4 zn[2])
{
#pragma unroll
    for (int kk = 0; kk < 4; ++kk) {
#pragma unroll
        for (int s = 0; s < 3; ++s) {
            f16x8 a0 = *(const f16x8*)(wti +
                ((((s * 4 + kk) * 16 + wid * 2 + 0) * 64 + lane) << 3));
            f16x8 a1 = *(const f16x8*)(wti +
                ((((s * 4 + kk) * 16 + wid * 2 + 1) * 64 + lane) << 3));
            int r = l16 + s;
            int base = r * 256 + ((((kk * 4 + g) ^ (r & 7)) << 4));
            f16x8 b0 = *(const f16x8*)(xp + base);
            f16x8 b1 = *(const f16x8*)(xp + 4608 + base);
            zn[0] = __builtin_amdgcn_mfma_f32_16x16x32_f16(a0, b0, zn[0], 0, 0, 0);
            zn[0] = __builtin_amdgcn_mfma_f32_16x16x32_f16(a0, b1, zn[0], 0, 0, 0);
            zn[1] = __builtin_amdgcn_mfma_f32_16x16x32_f16(a1, b0, zn[1], 0, 0, 0);
            zn[1] = __builtin_amdgcn_mfma_f32_16x16x32_f16(a1, b1, zn[1], 0, 0, 0);
        }
    }
}

// h-conv, single shift s: A-frags streamed from L2 (wt_h, L2-resident),
// B-frags from SINGLE-plane h-panel (h_{t-1} quantized to one f16).
__device__ __forceinline__ void hconv_s(const char* hp, const f16* __restrict__ wth,
                                        int s, int wid, int lane, int l16, int g,
                                        f32x4 hacc[2])
{
#pragma unroll
    for (int kk = 0; kk < 8; ++kk) {
        f16x8 a0 = *(const f16x8*)(wth +
            ((((s * 8 + kk) * 16 + wid * 2 + 0) * 64 + lane) << 3));
        f16x8 a1 = *(const f16x8*)(wth +
            ((((s * 8 + kk) * 16 + wid * 2 + 1) * 64 + lane) << 3));
        int r = l16 + s;
        int base = r * 512 + ((((kk * 4 + g) ^ (r & 7)) << 4));
        f16x8 b0 = *(const f16x8*)(hp + base);
        hacc[0] = __builtin_amdgcn_mfma_f32_16x16x32_f16(a0, b0, hacc[0], 0, 0, 0);
        hacc[1] = __builtin_amdgcn_mfma_f32_16x16x32_f16(a1, b0, hacc[1], 0, 0, 0);
    }
}

// ---------------- Fused persistent kernel ----------------
// 128 blocks = 16 b x 8 l-windows; 512 thr = 8 waves, wave owns 32 h (h16 = wid*2+hf).
// Cross-block handoff: self-timestamped halo mailbox (u64 {tag, f32 bits}, relaxed sc1
// atomics; tag+value atomic together; double-buffered by t&1; skew <= 1 step).
// h_{t-1} panel is single f16 (halves h-conv MFMA + LDS + epilogue); x stays hi/lo.
__global__ void __launch_bounds__(512)
rnn_fused(const float* __restrict__ x, const f16* __restrict__ wti,
          const f16* __restrict__ wth, float* __restrict__ out,
          u64* __restrict__ mbox)
{
    __shared__ __align__(16) char smem[36864];
    const int tid  = threadIdx.x;
    const int lane = tid & 63, wid = tid >> 6;   // 8 waves
    const int b    = blockIdx.x & 15;
    const int lw   = blockIdx.x >> 4;            // 0..7
    const int l0   = lw * 16;
    const int l16  = lane & 15, g = lane >> 4;
    const long HL  = (long)HOUT * LDIM;
    float* outb    = out + (long)b * (64 * HL);
    const float* xb = x + (long)b * (64L * 128 * LDIM);

    // publish duty for this thread's column (l0 + l16)
    int edge = -1;
    if (l16 == 0  && lw > 0) edge = 0;   // left edge -> consumed by lw-1
    if (l16 == 15 && lw < 7) edge = 1;   // right edge -> consumed by lw+1
    u64* mb_pub = (edge >= 0) ? (mbox + (((b * 8 + lw) * 2 + edge) * 2) * 256) : nullptr;

    // ---- prologue: stage x[0], x[1]; Z_0 into zcur
    stage_x(smem + XB0, xb, l0, tid);
    stage_x(smem + XB0 + 9216, xb + 128 * LDIM, l0, tid);
    __syncthreads();
    f32x4 zcur[2] = {};
    zconv(smem + XB0, wti, wid, lane, l16, g, zcur);
    __syncthreads();   // protect x-panel 0 rewrite at t=0

    for (int t = 0; t < 64; ++t) {
        float* outt = outb + (long)t * HL;

        // ---- stage x[t+2] (independent of recurrence)
        if (t + 2 < 64)
            stage_x(smem + XB0 + (t & 1) * 9216, xb + (long)(t + 2) * (128 * LDIM), l0, tid);

        // ---- Z_{t+1} from the x-panel staged at t-1
        f32x4 zn[2] = {};
        if (t < 63)
            zconv(smem + XB0 + ((t + 1) & 1) * 9216, wti, wid, lane, l16, g, zn);

        // ---- h-conv s=1 (rows 1..16 only: own columns, no halo)
        f32x4 hacc[2] = {};
        char* hp = smem + ((t ^ 1) & 1) * 9216;   // panel holding h_{t-1}
        if (t > 0)
            hconv_s(hp, wth, 1, wid, lane, l16, g, hacc);

        // ---- halo: poll self-timestamped mailbox (tag >= t), write rows 0/17 (single f16)
        if (t > 0) {
            const int par = (t ^ 1) & 1;           // slot parity of h_{t-1}
            if (tid < 256) {
                int c = tid;
                float xx = 0.f;
                if (lw > 0) {
                    const u64* p = mbox + ((((b * 8 + lw - 1) * 2 + 1) * 2 + par) * 256) + c;
                    u64 v = ld_mb(p);
                    while ((unsigned)(v >> 32) < (unsigned)t) {
                        __builtin_amdgcn_s_sleep(1);
                        v = ld_mb(p);
                    }
                    xx = __uint_as_float((unsigned)v);
                }
                int off = ((c >> 3) << 4) + (c & 7) * 2;                     // r=0
                *(f16*)(hp + off) = (f16)xx;
            } else {
                int c = tid - 256;
                float xx = 0.f;
                if (lw < 7) {
                    const u64* p = mbox + ((((b * 8 + lw + 1) * 2 + 0) * 2 + par) * 256) + c;
                    u64 v = ld_mb(p);
                    while ((unsigned)(v >> 32) < (unsigned)t) {
                        __builtin_amdgcn_s_sleep(1);
                        v = ld_mb(p);
                    }
                    xx = __uint_as_float((unsigned)v);
                }
                int off = 17 * 512 + ((((c >> 3) ^ 1) << 4)) + (c & 7) * 2;  // r=17
                *(f16*)(hp + off) = (f16)xx;
            }
        }
        __syncthreads();   // halo rows visible to all waves

        // ---- h-conv s=0,2 (use halo rows)
        if (t > 0) {
            hconv_s(hp, wth, 0, wid, lane, l16, g, hacc);
            hconv_s(hp, wth, 2, wid, lane, l16, g, hacc);
        }

        // ---- epilogue: h_t = tanh(hconv + Z_t)
        //  order: tanh -> mailbox publish (edges, earliest) -> out stores -> panel write
        char* pw = smem + (t & 1) * 9216;
        u64* pub = (edge >= 0) ? (mb_pub + (t & 1) * 256) : nullptr;
        const u64 tagw = ((u64)(unsigned)(t + 1)) << 32;
        const int r  = l16 + 1;
        const int rx = r & 7;
        float hv[2][4];
#pragma unroll
        for (int hf = 0; hf < 2; ++hf)
#pragma unroll
            for (int vv = 0; vv < 4; ++vv)
                hv[hf][vv] = tanh_fast(hacc[hf][vv] + zcur[hf][vv]);

        if (edge >= 0) {
#pragma unroll
            for (int hf = 0; hf < 2; ++hf)
#pragma unroll
                for (int vv = 0; vv < 4; ++vv) {
                    int c = wid * 32 + hf * 16 + g * 4 + vv;
                    st_mb(&pub[c], tagw | (u64)__float_as_uint(hv[hf][vv]));
                }
        }
#pragma unroll
        for (int hf = 0; hf < 2; ++hf)
#pragma unroll
            for (int vv = 0; vv < 4; ++vv) {
                int c = wid * 32 + hf * 16 + g * 4 + vv;
                outt[(long)c * LDIM + l0 + l16] = hv[hf][vv];   // plain store
            }
#pragma unroll
        for (int hf = 0; hf < 2; ++hf)
#pragma unroll
            for (int p = 0; p < 2; ++p) {
                int c = wid * 32 + hf * 16 + g * 4 + p * 2;
                int off = r * 512 + ((((c >> 3) ^ rx) << 4)) + (c & 7) * 2;
                f16x2 hw; hw[0] = (f16)hv[hf][2 * p]; hw[1] = (f16)hv[hf][2 * p + 1];
                *(f16x2*)(pw + off) = hw;
            }
        zcur[0] = zn[0];
        zcur[1] = zn[1];

        __syncthreads();   // protect h-panel(t&1) and x-panel reuse next step
    }
}

extern "C" void kernel_launch(void* const* d_in, const int* in_sizes, int n_in,
                              void* d_out, int out_size, void* d_ws, size_t ws_size,
                              hipStream_t stream)
{
    const float* x   = (const float*)d_in[0];   // [16][64][128][128]
    const float* W_i = (const float*)d_in[1];   // [256][128][3]
    const float* W_h = (const float*)d_in[2];   // [256][256][3]
    float* out = (float*)d_out;                 // [16][64][256][128]

    f16* wt_i = (f16*)d_ws;                              // 196608 B
    f16* wt_h = (f16*)((char*)d_ws + 196608);            // 393216 B
    u64* mbox = (u64*)((char*)d_ws + 589824);            // 16*8*2*2*256*8 = 131072 B

    prep_w<<<1152, 256, 0, stream>>>(W_i, wt_i, W_h, wt_h);
    hipMemsetAsync(mbox, 0, 131072, stream);             // tags <- 0 (< any awaited t)

    rnn_fused<<<128, 512, 0, stream>>>(x, wt_i, wt_h, out, mbox);
}